// Round 7
// baseline (499.729 us; speedup 1.0000x reference)
//
#include <hip/hip_runtime.h>
#include <hip/hip_cooperative_groups.h>
#include <math.h>

#define H 1024
#define S 32768
#define GRID2 2048
#define TPB 256

typedef float f32x4 __attribute__((ext_vector_type(4)));

// ---------------------------------------------------------------------------
// D1: v[h] = sum_o W[o,h] * hidden[o]  (+ zero the cross-block done flag;
// kernel-boundary coherence makes the zero visible to D2 everywhere).
// 64 blocks x 256 threads; W via nontemporal loads (proven -7us in r6).
// ---------------------------------------------------------------------------
__global__ void matvec_v_kernel(const float* __restrict__ W,
                                const float* __restrict__ hidden,
                                float* __restrict__ v,
                                unsigned int* __restrict__ done) {
    __shared__ float sh[H];
    __shared__ float4 red[256];
    const int t = threadIdx.x;
    const int b = blockIdx.x;
    if (b == 0 && t == 0) *done = 0u;
    const int c = t & 3;        // float4 col-group within the 16-col slice
    const int j = t >> 2;       // row class 0..63

    *reinterpret_cast<float4*>(&sh[t * 4]) =
        *reinterpret_cast<const float4*>(&hidden[t * 4]);
    __syncthreads();

    const int colbase = b * 16 + c * 4;
    float4 acc = make_float4(0.f, 0.f, 0.f, 0.f);
#pragma unroll
    for (int k = 0; k < 16; ++k) {
        const int o = j + 64 * k;
        const float hv = sh[o];
        const f32x4 w = __builtin_nontemporal_load(
            reinterpret_cast<const f32x4*>(&W[(size_t)o * H + colbase]));
        acc.x += hv * w.x; acc.y += hv * w.y;
        acc.z += hv * w.z; acc.w += hv * w.w;
    }
    red[t] = acc;
    __syncthreads();
#pragma unroll
    for (int off = 128; off >= 4; off >>= 1) {
        if (t < off) {
            float4 a = red[t], bb = red[t + off];
            a.x += bb.x; a.y += bb.y; a.z += bb.z; a.w += bb.w;
            red[t] = a;
        }
        __syncthreads();
    }
    if (t < 4)
        *reinterpret_cast<float4*>(&v[b * 16 + t * 4]) = red[t];
}

// ---------------------------------------------------------------------------
// D2 (fused energies + finalize), cooperative launch for residency guarantee.
// 2048 blocks x 256 threads = exactly 8 blocks/CU. Each block: 16 rows.
// Energies stay in REGISTERS; only (m_b, s_b) partials cross blocks.
// Cross-block sync: per-block coherent atomic stores + RELEASE atomicAdd on
// `done`, t0 ACQUIRE-polls to 2048, then each block redundantly reduces the
// 16 KB of partials via coalesced device-scope atomic loads (bypass stale
// per-XCD L2). NO grid.sync() (measured ~187us/sync in round 1).
// ---------------------------------------------------------------------------
extern "C" __global__ void __launch_bounds__(TPB, 8)
energies_finalize_kernel(const float* __restrict__ enc,
                         const float* __restrict__ v,
                         float* __restrict__ mpart,
                         float* __restrict__ spart,
                         unsigned int* __restrict__ done,
                         float* __restrict__ out) {
    __shared__ float sv[H];
    __shared__ float lm[4], ls[4];
    __shared__ float rm[4], rs[4];
    const int t = threadIdx.x;
    const int wave = t >> 6;
    const int lane = t & 63;
    const int grp  = lane >> 4;   // row within wave's 4
    const int gl   = lane & 15;   // lane within group

    *reinterpret_cast<float4*>(&sv[t * 4]) =
        *reinterpret_cast<const float4*>(&v[t * 4]);

    const int row = blockIdx.x * 16 + wave * 4 + grp;
    const f32x4* rp = reinterpret_cast<const f32x4*>(
        enc + (size_t)row * H + gl * 4);
    __syncthreads();

    f32x4 ev[8];
    float acc = 0.f;
#pragma unroll
    for (int s = 0; s < 8; ++s)
        ev[s] = __builtin_nontemporal_load(rp + s * 16);
#pragma unroll
    for (int s = 0; s < 8; ++s) {
        const float4 vv = *reinterpret_cast<const float4*>(&sv[s * 64 + gl * 4]);
        acc += ev[s].x * vv.x + ev[s].y * vv.y + ev[s].z * vv.z + ev[s].w * vv.w;
    }
#pragma unroll
    for (int s = 0; s < 8; ++s)
        ev[s] = __builtin_nontemporal_load(rp + (s + 8) * 16);
#pragma unroll
    for (int s = 0; s < 8; ++s) {
        const float4 vv = *reinterpret_cast<const float4*>(&sv[(s + 8) * 64 + gl * 4]);
        acc += ev[s].x * vv.x + ev[s].y * vv.y + ev[s].z * vv.z + ev[s].w * vv.w;
    }

    // row sum within 16-lane group (all 16 lanes end with the row energy)
#pragma unroll
    for (int off = 1; off <= 8; off <<= 1)
        acc += __shfl_xor(acc, off, 64);

    // cross-group fused softmax partial for the wave's 4 rows
    float mw = acc;
    mw = fmaxf(mw, __shfl_xor(mw, 16, 64));
    mw = fmaxf(mw, __shfl_xor(mw, 32, 64));
    float sw = __expf(acc - mw);
    sw += __shfl_xor(sw, 16, 64);
    sw += __shfl_xor(sw, 32, 64);

    if (lane == 0) { lm[wave] = mw; ls[wave] = sw; }
    __syncthreads();

    // ---- publish block partial + arrive; t0 polls to completion ----
    if (t == 0) {
        const float m = fmaxf(fmaxf(lm[0], lm[1]), fmaxf(lm[2], lm[3]));
        const float s = ls[0] * __expf(lm[0] - m) + ls[1] * __expf(lm[1] - m) +
                        ls[2] * __expf(lm[2] - m) + ls[3] * __expf(lm[3] - m);
        __hip_atomic_store(&mpart[blockIdx.x], m, __ATOMIC_RELAXED,
                           __HIP_MEMORY_SCOPE_AGENT);
        __hip_atomic_store(&spart[blockIdx.x], s, __ATOMIC_RELAXED,
                           __HIP_MEMORY_SCOPE_AGENT);
        __hip_atomic_fetch_add(done, 1u, __ATOMIC_RELEASE,
                               __HIP_MEMORY_SCOPE_AGENT);
        while (__hip_atomic_load(done, __ATOMIC_ACQUIRE,
                                 __HIP_MEMORY_SCOPE_AGENT) < GRID2)
            __builtin_amdgcn_s_sleep(8);
    }
    __syncthreads();

    // ---- per-block redundant finalize over the 2048 (m,s) partials ----
    // coalesced device-scope loads: thread t reads index k*256+t (wave reads
    // 256 B contiguous), bypassing possibly-stale per-XCD L2.
    float mv[8], s8[8];
#pragma unroll
    for (int k = 0; k < 8; ++k)
        mv[k] = __hip_atomic_load(&mpart[k * 256 + t], __ATOMIC_RELAXED,
                                  __HIP_MEMORY_SCOPE_AGENT);
#pragma unroll
    for (int k = 0; k < 8; ++k)
        s8[k] = __hip_atomic_load(&spart[k * 256 + t], __ATOMIC_RELAXED,
                                  __HIP_MEMORY_SCOPE_AGENT);

    float mt = mv[0];
#pragma unroll
    for (int k = 1; k < 8; ++k) mt = fmaxf(mt, mv[k]);
#pragma unroll
    for (int off = 32; off > 0; off >>= 1)
        mt = fmaxf(mt, __shfl_xor(mt, off, 64));
    if (lane == 0) rm[wave] = mt;
    __syncthreads();
    const float gm = fmaxf(fmaxf(rm[0], rm[1]), fmaxf(rm[2], rm[3]));

    float st = 0.f;
#pragma unroll
    for (int k = 0; k < 8; ++k) st += s8[k] * __expf(mv[k] - gm);
#pragma unroll
    for (int off = 32; off > 0; off >>= 1)
        st += __shfl_xor(st, off, 64);
    if (lane == 0) rs[wave] = st;
    __syncthreads();
    const float inv = 1.0f / (rs[0] + rs[1] + rs[2] + rs[3]);

    // each 16-lane group's lane 0 writes its row's output
    if (gl == 0) out[row] = __expf(acc - gm) * inv;
}

// ===========================================================================
// Fallback: proven round-6 3-dispatch pipeline (199.4 us) if coop launch is
// rejected. energies buffer used only here.
// ===========================================================================
__global__ void energies_kernel(const float* __restrict__ enc,
                                const float* __restrict__ v,
                                float* __restrict__ energies,
                                float* __restrict__ mpart,
                                float* __restrict__ spart) {
    __shared__ float sv[H];
    __shared__ float lm[4], ls[4];
    const int t = threadIdx.x;
    const int wave = t >> 6;
    const int lane = t & 63;
    const int grp  = lane >> 4;
    const int gl   = lane & 15;

    *reinterpret_cast<float4*>(&sv[t * 4]) =
        *reinterpret_cast<const float4*>(&v[t * 4]);

    const int row = blockIdx.x * 16 + wave * 4 + grp;
    const f32x4* rp = reinterpret_cast<const f32x4*>(
        enc + (size_t)row * H + gl * 4);
    __syncthreads();

    f32x4 ev[8];
    float acc = 0.f;
#pragma unroll
    for (int s = 0; s < 8; ++s)
        ev[s] = __builtin_nontemporal_load(rp + s * 16);
#pragma unroll
    for (int s = 0; s < 8; ++s) {
        const float4 vv = *reinterpret_cast<const float4*>(&sv[s * 64 + gl * 4]);
        acc += ev[s].x * vv.x + ev[s].y * vv.y + ev[s].z * vv.z + ev[s].w * vv.w;
    }
#pragma unroll
    for (int s = 0; s < 8; ++s)
        ev[s] = __builtin_nontemporal_load(rp + (s + 8) * 16);
#pragma unroll
    for (int s = 0; s < 8; ++s) {
        const float4 vv = *reinterpret_cast<const float4*>(&sv[(s + 8) * 64 + gl * 4]);
        acc += ev[s].x * vv.x + ev[s].y * vv.y + ev[s].z * vv.z + ev[s].w * vv.w;
    }
#pragma unroll
    for (int off = 1; off <= 8; off <<= 1)
        acc += __shfl_xor(acc, off, 64);

    float mw = acc;
    mw = fmaxf(mw, __shfl_xor(mw, 16, 64));
    mw = fmaxf(mw, __shfl_xor(mw, 32, 64));
    float sw = __expf(acc - mw);
    sw += __shfl_xor(sw, 16, 64);
    sw += __shfl_xor(sw, 32, 64);

    if (gl == 0) energies[row] = acc;
    if (lane == 0) { lm[wave] = mw; ls[wave] = sw; }
    __syncthreads();
    if (t == 0) {
        const float m = fmaxf(fmaxf(lm[0], lm[1]), fmaxf(lm[2], lm[3]));
        const float s = ls[0] * __expf(lm[0] - m) + ls[1] * __expf(lm[1] - m) +
                        ls[2] * __expf(lm[2] - m) + ls[3] * __expf(lm[3] - m);
        mpart[blockIdx.x] = m;
        spart[blockIdx.x] = s;
    }
}

__global__ void finalize_kernel(const float* __restrict__ energies,
                                const float* __restrict__ mpart,
                                const float* __restrict__ spart,
                                float* __restrict__ out) {
    const int t = threadIdx.x;
    const int lane = t & 63;
    const int wave = t >> 6;
    __shared__ float rm[4], rs[4];

    const float4 ma = *reinterpret_cast<const float4*>(&mpart[t * 8]);
    const float4 mb = *reinterpret_cast<const float4*>(&mpart[t * 8 + 4]);
    const float4 sa = *reinterpret_cast<const float4*>(&spart[t * 8]);
    const float4 sb = *reinterpret_cast<const float4*>(&spart[t * 8 + 4]);

    float mt = fmaxf(fmaxf(fmaxf(ma.x, ma.y), fmaxf(ma.z, ma.w)),
                     fmaxf(fmaxf(mb.x, mb.y), fmaxf(mb.z, mb.w)));
#pragma unroll
    for (int off = 32; off > 0; off >>= 1)
        mt = fmaxf(mt, __shfl_xor(mt, off, 64));
    if (lane == 0) rm[wave] = mt;
    __syncthreads();
    const float gm = fmaxf(fmaxf(rm[0], rm[1]), fmaxf(rm[2], rm[3]));

    float st = sa.x * __expf(ma.x - gm) + sa.y * __expf(ma.y - gm) +
               sa.z * __expf(ma.z - gm) + sa.w * __expf(ma.w - gm) +
               sb.x * __expf(mb.x - gm) + sb.y * __expf(mb.y - gm) +
               sb.z * __expf(mb.z - gm) + sb.w * __expf(mb.w - gm);
#pragma unroll
    for (int off = 32; off > 0; off >>= 1)
        st += __shfl_xor(st, off, 64);
    if (lane == 0) rs[wave] = st;
    __syncthreads();
    const float inv = 1.0f / (rs[0] + rs[1] + rs[2] + rs[3]);

    const int i = blockIdx.x * 256 + t;
    out[i] = __expf(energies[i] - gm) * inv;
}

// ---------------------------------------------------------------------------
// Launch: D1 (matvec + flag zero) then cooperative fused D2.
// ---------------------------------------------------------------------------
extern "C" void kernel_launch(void* const* d_in, const int* in_sizes, int n_in,
                              void* d_out, int out_size, void* d_ws, size_t ws_size,
                              hipStream_t stream) {
    const float* hidden = (const float*)d_in[0];   // [1024]
    const float* enc    = (const float*)d_in[1];   // [32768, 1024]
    const float* W      = (const float*)d_in[2];   // [1024, 1024]
    // d_in[3] = b: (b . hidden) is constant across s -> cancels in softmax.
    float* out = (float*)d_out;                    // [32768]

    float* v        = (float*)d_ws;          // 1024
    float* mpart    = v + H;                 // 2048
    float* spart    = mpart + 2048;          // 2048
    unsigned int* done = (unsigned int*)(spart + 2048);  // 1 (+pad)
    float* energies = (float*)(done + 16);   // 32768 (fallback only)

    matvec_v_kernel<<<64, 256, 0, stream>>>(W, hidden, v, done);

    void* args[] = { (void*)&enc, (void*)&v, (void*)&mpart, (void*)&spart,
                     (void*)&done, (void*)&out };
    hipError_t err = hipLaunchCooperativeKernel(
        reinterpret_cast<void*>(energies_finalize_kernel),
        dim3(GRID2), dim3(TPB), args, 0, stream);

    if (err != hipSuccess) {
        // fallback: proven round-6 pipeline (199.4 us)
        energies_kernel<<<2048, 256, 0, stream>>>(enc, v, energies, mpart, spart);
        finalize_kernel<<<128, 256, 0, stream>>>(energies, mpart, spart, out);
    }
}

// Round 8
// 199.274 us; speedup vs baseline: 2.5078x; 2.5078x over previous
//
#include <hip/hip_runtime.h>
#include <math.h>

#define H 1024
#define S 32768

typedef float f32x4 __attribute__((ext_vector_type(4)));

// ---------------------------------------------------------------------------
// PROVEN round-6 pipeline (199.4 us). Rounds 1 & 7 measured in-kernel
// cross-XCD sync (grid.sync / hand-rolled atomic barrier) at 187-270 us =
// coherence storm across 8 XCDs. Kernel boundaries (~8 us) are the cheapest
// global barrier on MI355X — 3 dispatches is the optimal structure.
// ---------------------------------------------------------------------------

// Stage 1: v[h] = sum_o W[o,h] * hidden[o], one dispatch.
// 64 blocks x 256 threads. Block b owns cols [b*16, b*16+16).
// W via NONTEMPORAL loads: streamed once, no L2/IF allocation -> avoids
// forcing eviction-writebacks of the 512 MiB poison fill's dirty lines
// inside the timed window (measured -7 us in round 6).
__global__ void matvec_v_kernel(const float* __restrict__ W,
                                const float* __restrict__ hidden,
                                float* __restrict__ v) {
    __shared__ float sh[H];
    __shared__ float4 red[256];
    const int t = threadIdx.x;
    const int b = blockIdx.x;
    const int c = t & 3;        // float4 col-group within the 16-col slice
    const int j = t >> 2;       // row class 0..63

    *reinterpret_cast<float4*>(&sh[t * 4]) =
        *reinterpret_cast<const float4*>(&hidden[t * 4]);
    __syncthreads();

    const int colbase = b * 16 + c * 4;
    float4 acc = make_float4(0.f, 0.f, 0.f, 0.f);
#pragma unroll
    for (int k = 0; k < 16; ++k) {
        const int o = j + 64 * k;
        const float hv = sh[o];
        const f32x4 w = __builtin_nontemporal_load(
            reinterpret_cast<const f32x4*>(&W[(size_t)o * H + colbase]));
        acc.x += hv * w.x; acc.y += hv * w.y;
        acc.z += hv * w.z; acc.w += hv * w.w;
    }
    red[t] = acc;
    __syncthreads();
#pragma unroll
    for (int off = 128; off >= 4; off >>= 1) {
        if (t < off) {
            float4 a = red[t], bb = red[t + off];
            a.x += bb.x; a.y += bb.y; a.z += bb.z; a.w += bb.w;
            red[t] = a;
        }
        __syncthreads();
    }
    if (t < 4)
        *reinterpret_cast<float4*>(&v[b * 16 + t * 4]) = red[t];
}

// Stage 2: energies + per-block online-softmax partials.
// 2048 blocks x 256 threads; each 16-lane group owns ONE row (16 rows/block).
// enc loads NONTEMPORAL (read exactly once; nt misses don't allocate in IF,
// so no forced eviction of dirty fill lines during our window).
__global__ void energies_kernel(const float* __restrict__ enc,
                                const float* __restrict__ v,
                                float* __restrict__ energies,
                                float* __restrict__ mpart,
                                float* __restrict__ spart) {
    __shared__ float sv[H];
    __shared__ float lm[4], ls[4];
    const int t = threadIdx.x;
    const int wave = t >> 6;
    const int lane = t & 63;
    const int grp  = lane >> 4;   // row within wave's 4
    const int gl   = lane & 15;   // lane within group

    *reinterpret_cast<float4*>(&sv[t * 4]) =
        *reinterpret_cast<const float4*>(&v[t * 4]);

    const int row = blockIdx.x * 16 + wave * 4 + grp;
    const f32x4* rp = reinterpret_cast<const f32x4*>(
        enc + (size_t)row * H + gl * 4);   // stride between segments: 16 f32x4
    __syncthreads();

    f32x4 ev[8];
    float acc = 0.f;

    // first 8 segments: hoist nt loads, then FMA against LDS v
#pragma unroll
    for (int s = 0; s < 8; ++s)
        ev[s] = __builtin_nontemporal_load(rp + s * 16);
#pragma unroll
    for (int s = 0; s < 8; ++s) {
        const float4 vv = *reinterpret_cast<const float4*>(&sv[s * 64 + gl * 4]);
        acc += ev[s].x * vv.x + ev[s].y * vv.y + ev[s].z * vv.z + ev[s].w * vv.w;
    }
    // second 8 segments
#pragma unroll
    for (int s = 0; s < 8; ++s)
        ev[s] = __builtin_nontemporal_load(rp + (s + 8) * 16);
#pragma unroll
    for (int s = 0; s < 8; ++s) {
        const float4 vv = *reinterpret_cast<const float4*>(&sv[(s + 8) * 64 + gl * 4]);
        acc += ev[s].x * vv.x + ev[s].y * vv.y + ev[s].z * vv.z + ev[s].w * vv.w;
    }

    // row sum within 16-lane group (all 16 lanes end with the row sum)
#pragma unroll
    for (int off = 1; off <= 8; off <<= 1)
        acc += __shfl_xor(acc, off, 64);

    // cross-group fused softmax partial: max then sum of exp over the 4 rows
    float mw = acc;
    mw = fmaxf(mw, __shfl_xor(mw, 16, 64));
    mw = fmaxf(mw, __shfl_xor(mw, 32, 64));
    float sw = __expf(acc - mw);
    sw += __shfl_xor(sw, 16, 64);
    sw += __shfl_xor(sw, 32, 64);

    if (gl == 0) energies[row] = acc;          // 4 consecutive rows per wave
    if (lane == 0) { lm[wave] = mw; ls[wave] = sw; }
    __syncthreads();
    if (t == 0) {
        const float m = fmaxf(fmaxf(lm[0], lm[1]), fmaxf(lm[2], lm[3]));
        const float s = ls[0] * __expf(lm[0] - m) + ls[1] * __expf(lm[1] - m) +
                        ls[2] * __expf(lm[2] - m) + ls[3] * __expf(lm[3] - m);
        mpart[blockIdx.x] = m;
        spart[blockIdx.x] = s;
    }
}

// Stage 3: finalize, parallel. 128 blocks x 256 threads.
// Every block redundantly reduces the 2048 (m,s) partials (16 KB, cache-
// resident) then writes its own 256 outputs. energies[] reads stay normal
// (freshly written -> L2/IF hits; nt would forfeit them).
__global__ void finalize_kernel(const float* __restrict__ energies,
                                const float* __restrict__ mpart,
                                const float* __restrict__ spart,
                                float* __restrict__ out) {
    const int t = threadIdx.x;
    const int lane = t & 63;
    const int wave = t >> 6;
    __shared__ float rm[4], rs[4];

    const float4 ma = *reinterpret_cast<const float4*>(&mpart[t * 8]);
    const float4 mb = *reinterpret_cast<const float4*>(&mpart[t * 8 + 4]);
    const float4 sa = *reinterpret_cast<const float4*>(&spart[t * 8]);
    const float4 sb = *reinterpret_cast<const float4*>(&spart[t * 8 + 4]);

    float mt = fmaxf(fmaxf(fmaxf(ma.x, ma.y), fmaxf(ma.z, ma.w)),
                     fmaxf(fmaxf(mb.x, mb.y), fmaxf(mb.z, mb.w)));
#pragma unroll
    for (int off = 32; off > 0; off >>= 1)
        mt = fmaxf(mt, __shfl_xor(mt, off, 64));
    if (lane == 0) rm[wave] = mt;
    __syncthreads();
    const float gm = fmaxf(fmaxf(rm[0], rm[1]), fmaxf(rm[2], rm[3]));

    float st = sa.x * __expf(ma.x - gm) + sa.y * __expf(ma.y - gm) +
               sa.z * __expf(ma.z - gm) + sa.w * __expf(ma.w - gm) +
               sb.x * __expf(mb.x - gm) + sb.y * __expf(mb.y - gm) +
               sb.z * __expf(mb.z - gm) + sb.w * __expf(mb.w - gm);
#pragma unroll
    for (int off = 32; off > 0; off >>= 1)
        st += __shfl_xor(st, off, 64);
    if (lane == 0) rs[wave] = st;
    __syncthreads();
    const float inv = 1.0f / (rs[0] + rs[1] + rs[2] + rs[3]);

    const int i = blockIdx.x * 256 + t;      // 128*256 = 32768 = S
    out[i] = __expf(energies[i] - gm) * inv;
}

// ---------------------------------------------------------------------------
// Launch: 3 dispatches; kernel boundaries are the barriers.
// In-kernel cross-XCD sync is closed: grid.sync() ~187 us (R1), hand-rolled
// atomic barrier ~250 us (R7) — device-scope coherence storm across 8 XCDs.
// ---------------------------------------------------------------------------
extern "C" void kernel_launch(void* const* d_in, const int* in_sizes, int n_in,
                              void* d_out, int out_size, void* d_ws, size_t ws_size,
                              hipStream_t stream) {
    const float* hidden = (const float*)d_in[0];   // [1024]
    const float* enc    = (const float*)d_in[1];   // [32768, 1024]
    const float* W      = (const float*)d_in[2];   // [1024, 1024]
    // d_in[3] = b: (b . hidden) is constant across s -> cancels in softmax.
    float* out = (float*)d_out;                    // [32768]

    float* v        = (float*)d_ws;        // 1024
    float* energies = v + H;               // 32768
    float* mpart    = energies + S;        // 2048
    float* spart    = mpart + 2048;        // 2048

    matvec_v_kernel<<<64, 256, 0, stream>>>(W, hidden, v);
    energies_kernel<<<2048, 256, 0, stream>>>(enc, v, energies, mpart, spart);
    finalize_kernel<<<128, 256, 0, stream>>>(energies, mpart, spart, out);
}